// Round 14
// baseline (253.778 us; speedup 1.0000x reference)
//
#include <hip/hip_runtime.h>
#include <hip/hip_bf16.h>
#include <math.h>

#define NEGV (-1e10f)

typedef __attribute__((ext_vector_type(8))) short bf16x8;
typedef __attribute__((ext_vector_type(4))) float f32x4;
typedef __attribute__((ext_vector_type(16))) float f32x16;

static __device__ __forceinline__ unsigned short f2bf(float f) {
  unsigned int u = __builtin_bit_cast(unsigned int, f);
  unsigned int r = (u + 0x7fffu + ((u >> 16) & 1u)) >> 16;
  return (unsigned short)r;
}
static __device__ __forceinline__ float bf2f(unsigned short v) {
  return __builtin_bit_cast(float, (unsigned int)v << 16);
}

#define GLD16(g, l)                                                   \
  __builtin_amdgcn_global_load_lds(                                   \
      (const __attribute__((address_space(1))) void*)(g),             \
      (__attribute__((address_space(3))) void*)(l), 16, 0, 0)

// ---------------------------------------------------------------------------
// K1: merged input casts (R10 structure). Blocks [0,2048): emb fp32->bf16 +
// attn-weight logits. Blocks [2048,3200): W_q/W_k fp32->bf16 with the R9 row
// permutation (same perm on both -> QK^T invariant). W_v is NOT cast — the
// V GEMM is algebraically eliminated (see rcomp/vproj).
// ---------------------------------------------------------------------------
__global__ __launch_bounds__(256) void cast_inputs(
    const float* __restrict__ emb, const int* __restrict__ tags,
    const float* __restrict__ ww, const float* __restrict__ wq,
    const float* __restrict__ wk, unsigned short* __restrict__ embbf,
    float* __restrict__ logits, unsigned short* __restrict__ wbf) {
  int bx = blockIdx.x;
  if (bx < 2048) {
    int w = threadIdx.x >> 6, lane = threadIdx.x & 63;
    int row = bx * 4 + w;  // 0..8191
    const float4* src = (const float4*)(emb + (size_t)row * 768);
    const float4* wsrc = (const float4*)ww;
    ushort4* dst = (ushort4*)(embbf + (size_t)row * 768);
    float d = 0.f;
#pragma unroll
    for (int j = 0; j < 3; j++) {
      int idx = lane + 64 * j;
      float4 v = src[idx];
      float4 wv = wsrc[idx];
      d += v.x * wv.x + v.y * wv.y + v.z * wv.z + v.w * wv.w;
      ushort4 o;
      o.x = f2bf(v.x); o.y = f2bf(v.y); o.z = f2bf(v.z); o.w = f2bf(v.w);
      dst[idx] = o;
    }
#pragma unroll
    for (int off = 32; off; off >>= 1) d += __shfl_xor(d, off);
    if (lane == 0) logits[row] = (tags[row] == 0) ? NEGV : d;
  } else {
    int g = bx - 2048;              // 0..1151
    int z = g / 576;                // 0 = W_q, 1 = W_k
    int idx = (g - z * 576) * 256 + threadIdx.x;  // float4 index
    const float* src = (z == 0) ? wq : wk;
    float4 v = ((const float4*)src)[idx];
    ushort4 o;
    o.x = f2bf(v.x); o.y = f2bf(v.y); o.z = f2bf(v.z); o.w = f2bf(v.w);
    int f = idx / 192;              // source feature row
    int col4 = idx - f * 192;
    int h = f & 7, dg = f >> 3;     // head, depth 0..95
    int tt = dg >> 4, ddl = dg & 15;
    int wn = ddl >> 3, cb = (ddl >> 2) & 1, j = ddl & 3;
    int orow = tt * 128 + wn * 64 + j * 16 + cb * 8 + h;
    ((ushort4*)(wbf + (size_t)z * 589824))[orow * 192 + col4] = o;
  }
}

// ---------------------------------------------------------------------------
// K2: softmax over s=1024 per batch of the masked logits -> aw
// ---------------------------------------------------------------------------
__global__ __launch_bounds__(256) void softmax_aw(
    const float* __restrict__ logits, float* __restrict__ aw) {
  __shared__ float red[4];
  int b = blockIdx.x, t = threadIdx.x;
  const float* L = logits + b * 1024;
  float x0 = L[t], x1 = L[t + 256], x2 = L[t + 512], x3 = L[t + 768];
  float m = fmaxf(fmaxf(x0, x1), fmaxf(x2, x3));
#pragma unroll
  for (int off = 32; off; off >>= 1) m = fmaxf(m, __shfl_xor(m, off));
  if ((t & 63) == 0) red[t >> 6] = m;
  __syncthreads();
  m = fmaxf(fmaxf(red[0], red[1]), fmaxf(red[2], red[3]));
  float e0 = __expf(x0 - m), e1 = __expf(x1 - m), e2 = __expf(x2 - m),
        e3 = __expf(x3 - m);
  float s = e0 + e1 + e2 + e3;
#pragma unroll
  for (int off = 32; off; off >>= 1) s += __shfl_xor(s, off);
  __syncthreads();
  if ((t & 63) == 0) red[t >> 6] = s;
  __syncthreads();
  float inv = 1.0f / (red[0] + red[1] + red[2] + red[3]);
  float* A = aw + b * 1024;
  A[t] = e0 * inv; A[t + 256] = e1 * inv;
  A[t + 512] = e2 * inv; A[t + 768] = e3 * inv;
}

// ---------------------------------------------------------------------------
// K3: Q/K projection GEMM (R10 kernel, V branch deleted; grid z in {0,1}).
// 128x128 tile, BK=32, global_load_lds width=16, prefetch-ahead dbuf, one
// barrier per K-iter. Q/K epilogue: b64 LDS writes (W row-perm) -> coalesced
// b128 global stores in the 32x32-attn-fragment layout:
// chunk = ((b*32+q/32)*8+h)*6 + d/16 (1KB), lane32 = (q%32)|(((d%16)>>3)<<5),
// elem = d%8 (d = permuted feature).
// ---------------------------------------------------------------------------
__global__ __launch_bounds__(256) void qkv_gemm(
    const unsigned short* __restrict__ A, const unsigned short* __restrict__ Wbf,
    unsigned short* __restrict__ Qf, unsigned short* __restrict__ Kf) {
  __shared__ __align__(16) unsigned short sm[17408];
  unsigned short* As = sm;         // dbuf: As + buf*4096
  unsigned short* Bs = sm + 8192;  // dbuf: Bs + buf*4096
  int z = blockIdx.z;
  const unsigned short* B = Wbf + (size_t)z * 589824;
  int mb = blockIdx.x * 128, nb = blockIdx.y * 128;
  int tid = threadIdx.x;
  int w = tid >> 6, lane = tid & 63;
  int wm = w >> 1, wn = w & 1;
  int c = lane & 15, quad = lane >> 4;
  int lrow = lane >> 2;
  int lcol = ((lane & 3) ^ (lrow & 3)) * 8;  // XOR-swizzled source chunk
  const unsigned short* Ag = A + (size_t)(mb + w * 32 + lrow) * 768 + lcol;
  const unsigned short* Bg = B + (size_t)(nb + w * 32 + lrow) * 768 + lcol;
  int woff = w * 1024;

#define PREFETCH(buf, kb)                                              \
  do {                                                                 \
    GLD16(Ag + (kb), As + (buf) * 4096 + woff);                        \
    GLD16(Ag + (kb) + 16 * 768, As + (buf) * 4096 + woff + 512);       \
    GLD16(Bg + (kb), Bs + (buf) * 4096 + woff);                        \
    GLD16(Bg + (kb) + 16 * 768, Bs + (buf) * 4096 + woff + 512);       \
  } while (0)

  f32x4 acc[4][4];
#pragma unroll
  for (int i = 0; i < 4; i++)
#pragma unroll
    for (int j = 0; j < 4; j++) acc[i][j] = 0;

  PREFETCH(0, 0);
  for (int it = 0; it < 24; it++) {
    __syncthreads();
    if (it + 1 < 24) PREFETCH((it + 1) & 1, (it + 1) * 32);
    const unsigned short* Ab = As + (it & 1) * 4096;
    const unsigned short* Bb = Bs + (it & 1) * 4096;
    int sw = (quad ^ (c & 3)) * 8;
    bf16x8 af[4], bfr[4];
#pragma unroll
    for (int i = 0; i < 4; i++)
      af[i] = *(const bf16x8*)&Ab[(wm * 64 + i * 16 + c) * 32 + sw];
#pragma unroll
    for (int j = 0; j < 4; j++)
      bfr[j] = *(const bf16x8*)&Bb[(wn * 64 + j * 16 + c) * 32 + sw];
#pragma unroll
    for (int i = 0; i < 4; i++)
#pragma unroll
      for (int j = 0; j < 4; j++)
        acc[i][j] = __builtin_amdgcn_mfma_f32_16x16x32_bf16(af[i], bfr[j],
                                                            acc[i][j], 0, 0, 0);
  }
  __syncthreads();  // staging reads done before epilogue reuses sm

  unsigned short* O = (z == 0) ? Qf : Kf;
#pragma unroll
  for (int i = 0; i < 4; i++) {
#pragma unroll
    for (int r = 0; r < 4; r++) {
      int qlr = wm * 64 + i * 16 + quad * 4 + r;  // 0..127
      int chunkL = (qlr >> 5) * 8 + (c & 7);      // 0..31
      int lane32 = (qlr & 31) + wn * 32;
      ushort4 pk;
      pk.x = f2bf(acc[i][0][r]);
      pk.y = f2bf(acc[i][1][r]);
      pk.z = f2bf(acc[i][2][r]);
      pk.w = f2bf(acc[i][3][r]);
      *(ushort4*)&sm[chunkL * 520 + lane32 * 8 + 4 * (c >> 3)] = pk;
    }
  }
  __syncthreads();
  int bq = mb >> 10;
  int qt32g0 = (mb & 1023) >> 5;
  int tt = blockIdx.y;  // d/16 chunk (0..5)
#pragma unroll
  for (int it2 = 0; it2 < 8; it2++) {
    int g = it2 * 256 + tid;
    int chunkL = g >> 6;
    int off = (g & 63) * 8;
    bf16x8 vdat = *(const bf16x8*)&sm[chunkL * 520 + off];
    int qt32 = qt32g0 + (chunkL >> 3), h = chunkL & 7;
    size_t dst = ((((size_t)(bq * 32 + qt32) * 8 + h) * 6 + tt) << 9) + off;
    *(bf16x8*)&O[dst] = vdat;
  }
#undef PREFETCH
}

// ---------------------------------------------------------------------------
// K4: attention (R10 version — measured best). Block = 64q x 64k x 8h, 4
// waves (2x2 of 32x32 via mfma_f32_32x32x16_bf16), barrier-free direct
// global->VGPR fragment loads, h-softmax without max-shift, XCD batch
// pinning (b = id&7). Writes aw-weighted h-softmax partials Ptp[qb][b][k][h].
// ---------------------------------------------------------------------------
__global__ __launch_bounds__(256) void attn(
    const unsigned short* __restrict__ Qf, const unsigned short* __restrict__ Kf,
    const float* __restrict__ aw, float* __restrict__ Ptp) {
  __shared__ float pbuf[1024];  // (wq*2+wk)*256 + kcol*8 + h
  int id = blockIdx.x;
  int b = id & 7, qb = (id >> 3) & 15, kb = id >> 7;
  int tid = threadIdx.x, w = tid >> 6, lane = tid & 63;
  int wq = w >> 1, wk = w & 1;
  const unsigned short* Qb =
      Qf + ((size_t)(b * 32 + qb * 2 + wq) * 48) * 512 + (size_t)lane * 8;
  const unsigned short* Kb =
      Kf + ((size_t)(b * 32 + kb * 2 + wk) * 48) * 512 + (size_t)lane * 8;

  f32x16 acc[8];
#pragma unroll
  for (int h = 0; h < 8; h++) acc[h] = 0;
#pragma unroll
  for (int h = 0; h < 8; h++) {
#pragma unroll
    for (int t = 0; t < 6; t++) {
      bf16x8 a = *(const bf16x8*)(Qb + (size_t)(h * 6 + t) * 512);
      bf16x8 bb = *(const bf16x8*)(Kb + (size_t)(h * 6 + t) * 512);
      acc[h] = __builtin_amdgcn_mfma_f32_32x32x16_bf16(a, bb, acc[h], 0, 0, 0);
    }
  }

  float awv[16];
#pragma unroll
  for (int reg = 0; reg < 16; reg++) {
    int row = (reg & 3) + 8 * (reg >> 2) + 4 * (lane >> 5);
    awv[reg] = aw[b * 1024 + qb * 64 + wq * 32 + row];
  }
  float partial[8];
#pragma unroll
  for (int h = 0; h < 8; h++) partial[h] = 0.f;
  const float C2 = 0.10206207261596577f * 1.4426950408889634f;  // /sqrt(96)*log2e
#pragma unroll
  for (int reg = 0; reg < 16; reg++) {
    float v[8];
    float ssum = 0.f;
#pragma unroll
    for (int h = 0; h < 8; h++) {
      float e = exp2f(acc[h][reg] * C2);  // no max-shift needed
      v[h] = e;
      ssum += e;
    }
    float g = awv[reg] * __builtin_amdgcn_rcpf(ssum);  // aw==0 for padded q
#pragma unroll
    for (int h = 0; h < 8; h++) partial[h] += v[h] * g;
  }
#pragma unroll
  for (int h = 0; h < 8; h++) {
    float v = partial[h];
    v += __shfl_xor(v, 32);
    partial[h] = v;
  }
  if (lane < 32) {
#pragma unroll
    for (int h = 0; h < 8; h++) pbuf[w * 256 + lane * 8 + h] = partial[h];
  }
  __syncthreads();
#pragma unroll
  for (int wk2 = 0; wk2 < 2; wk2++) {
    float s = pbuf[wk2 * 256 + tid] + pbuf[(2 + wk2) * 256 + tid];
    int kcol = tid >> 3, h = tid & 7;
    Ptp[(((size_t)qb * 8 + b) * 1024 + kb * 64 + wk2 * 32 + kcol) * 8 + h] = s;
  }
}

// ---------------------------------------------------------------------------
// K5: rcomp — fused qc-reduction + k-contraction:
//   Rp[kc][b][h][d] = sum_{k in kc-slice} (sum_qb Ptp[qb][b][k][h]) * emb[b,k,d]
// grid (16 kc, 8 b), block 192 (thread owns a d-quad). Replaces the V GEMM:
// out = Wv @ R (see vproj) since out[b,o] = sum_d Wv[o,d] sum_k P~ * emb.
// ---------------------------------------------------------------------------
__global__ __launch_bounds__(192) void rcomp(
    const float* __restrict__ Ptp, const unsigned short* __restrict__ embbf,
    float* __restrict__ Rp) {
  __shared__ float pbk[64 * 8];  // summed P~ for this k-slice
  int kc = blockIdx.x, b = blockIdx.y;
  int t = threadIdx.x;
  if (t < 64) {
    int k = kc * 64 + t;
    f32x4 s0 = 0, s1 = 0;
#pragma unroll
    for (int qc = 0; qc < 16; qc++) {
      const float* p = &Ptp[(((size_t)qc * 8 + b) * 1024 + k) * 8];
      s0 += *(const f32x4*)p;
      s1 += *(const f32x4*)(p + 4);
    }
    *(f32x4*)&pbk[t * 8] = s0;
    *(f32x4*)&pbk[t * 8 + 4] = s1;
  }
  __syncthreads();
  int d0 = t * 4;
  float acc[8][4];
#pragma unroll
  for (int h = 0; h < 8; h++)
#pragma unroll
    for (int j = 0; j < 4; j++) acc[h][j] = 0.f;
  const unsigned short* eb =
      embbf + ((size_t)(b * 1024 + kc * 64)) * 768 + d0;
#pragma unroll 4
  for (int k = 0; k < 64; k++) {
    ushort4 ev = *(const ushort4*)(eb + (size_t)k * 768);
    float e0 = bf2f(ev.x), e1 = bf2f(ev.y), e2 = bf2f(ev.z), e3 = bf2f(ev.w);
    const float* pr = &pbk[k * 8];
#pragma unroll
    for (int h = 0; h < 8; h++) {
      float p = pr[h];  // broadcast (same addr all lanes)
      acc[h][0] += p * e0;
      acc[h][1] += p * e1;
      acc[h][2] += p * e2;
      acc[h][3] += p * e3;
    }
  }
#pragma unroll
  for (int h = 0; h < 8; h++) {
    f32x4 o;
    o[0] = acc[h][0]; o[1] = acc[h][1]; o[2] = acc[h][2]; o[3] = acc[h][3];
    *(f32x4*)&Rp[(((size_t)kc * 8 + b) * 8 + h) * 768 + d0] = o;
  }
}

// ---------------------------------------------------------------------------
// K6: vproj — out[b,o] = sum_d Wv[o,d] * R[b,o&7,d], R = sum_kc Rp.
// grid (8 b), block 768 (thread = o). Wv read in fp32 (more accurate than
// the old bf16 V path). Plain stores -> no out zeroing needed.
// ---------------------------------------------------------------------------
__global__ __launch_bounds__(768) void vproj(
    const float* __restrict__ Rp, const float* __restrict__ wv,
    float* __restrict__ out) {
  __shared__ float Rs[8 * 772];  // stride 772: h*772 % 32 = h*4 -> no conflict
  int b = blockIdx.x, t = threadIdx.x;
#pragma unroll
  for (int i = 0; i < 8; i++) {
    float s = 0.f;
#pragma unroll
    for (int kc = 0; kc < 16; kc++)
      s += Rp[(((size_t)kc * 8 + b) * 8 + i) * 768 + t];
    Rs[i * 772 + t] = s;
  }
  __syncthreads();
  int h = t & 7;
  const float4* wr = (const float4*)(wv + (size_t)t * 768);
  const float* rr = &Rs[h * 772];
  float a = 0.f;
#pragma unroll 4
  for (int d4 = 0; d4 < 192; d4++) {
    float4 wvv = wr[d4];
    const float* r = rr + d4 * 4;
    a += wvv.x * r[0] + wvv.y * r[1] + wvv.z * r[2] + wvv.w * r[3];
  }
  out[b * 768 + t] = a;
}

// ---------------------------------------------------------------------------
extern "C" void kernel_launch(void* const* d_in, const int* in_sizes, int n_in,
                              void* d_out, int out_size, void* d_ws,
                              size_t ws_size, hipStream_t stream) {
  const float* emb = (const float*)d_in[0];
  const int* tags = (const int*)d_in[1];
  const float* ww = (const float*)d_in[2];
  const float* wq = (const float*)d_in[3];
  const float* wk = (const float*)d_in[4];
  const float* wv = (const float*)d_in[5];
  float* out = (float*)d_out;
  char* ws = (char*)d_ws;
  unsigned short* embbf = (unsigned short*)(ws + 0);           // 12,582,912
  unsigned short* wbf   = (unsigned short*)(ws + 12582912);    //  2,359,296 (Q,K)
  unsigned short* Qf    = (unsigned short*)(ws + 16121856);    // 12,582,912
  unsigned short* Kf    = (unsigned short*)(ws + 28704768);    // 12,582,912
  float* logits         = (float*)(ws + 53870592);             //     32,768
  float* aw             = (float*)(ws + 53903360);             //     32,768
  float* Ptp            = (float*)(ws + 53936128);             //  4,194,304
  float* Rp             = (float*)(ws + 58130432);             //  3,145,728

  cast_inputs<<<3200, 256, 0, stream>>>(emb, tags, ww, wq, wk, embbf, logits,
                                        wbf);
  softmax_aw<<<8, 256, 0, stream>>>(logits, aw);
  qkv_gemm<<<dim3(64, 6, 2), 256, 0, stream>>>(embbf, wbf, Qf, Kf);
  attn<<<2048, 256, 0, stream>>>(Qf, Kf, aw, Ptp);
  rcomp<<<dim3(16, 8), 192, 0, stream>>>(Ptp, embbf, Rp);
  vproj<<<8, 768, 0, stream>>>(Rp, wv, out);
}